// Round 16
// baseline (724.622 us; speedup 1.0000x reference)
//
#include <hip/hip_runtime.h>
#include <stdint.h>

#define N_ROWS 100000
#define D_IN 512
#define H_DIM 2048
#define HEADS 4
#define NSEG 10000

typedef unsigned short u16;
typedef __attribute__((ext_vector_type(4))) float f32x4;
typedef __attribute__((ext_vector_type(8))) __bf16 bf16x8;
typedef __attribute__((ext_vector_type(8))) u16 u16x8;
typedef __attribute__((ext_vector_type(4))) u16 u16x4;

__device__ __forceinline__ u16 f2bf(float f) {
  union { float f; uint32_t u; } v; v.f = f;
  uint32_t r = (v.u + 0x7FFF + ((v.u >> 16) & 1)) >> 16;
  return (u16)r;
}
__device__ __forceinline__ float bf2f(u16 u) {
  union { uint32_t u; float f; } v; v.u = ((uint32_t)u) << 16;
  return v.f;
}

// ---------------- init: bias1 = b1 + alpha*W1[512,:], zero segsum ----------
__global__ void init_misc(const float* __restrict__ W1, const float* __restrict__ b1,
                          const float* __restrict__ alpha, float* __restrict__ bias1,
                          float* __restrict__ segsum) {
  int i = blockIdx.x * 256 + threadIdx.x;
  if (i < NSEG * HEADS) segsum[i] = 0.f;
  if (i < H_DIM) bias1[i] = b1[i] + alpha[0] * W1[(size_t)D_IN * H_DIM + i];
}

// ---------------- transpose + cast: in[R][C] fp32 -> out[C][R] bf16 --------
__global__ __launch_bounds__(256) void transpose_cast(const float* __restrict__ in,
                                                      u16* __restrict__ outT,
                                                      int R, int Cc) {
  __shared__ float t[32][33];
  const int c0 = blockIdx.x * 32, r0 = blockIdx.y * 32;
  const int tx = threadIdx.x, ty = threadIdx.y;  // 32 x 8
#pragma unroll
  for (int i = 0; i < 4; ++i)
    t[ty + 8 * i][tx] = in[(size_t)(r0 + ty + 8 * i) * Cc + c0 + tx];
  __syncthreads();
#pragma unroll
  for (int i = 0; i < 4; ++i) {
    int oc = ty + 8 * i;
    outT[(size_t)(c0 + oc) * R + r0 + tx] = f2bf(t[tx][oc]);
  }
}

// ============================================================================
// NT GEMM — r11 structure (best known; see r12-r14 lessons in history) with
// AFP32 option: GEMM1 stages A directly as FP32 (x) and converts fp32->bf16
// at fragment-read time ((__bf16) casts -> v_cvt_pk_bf16_f32, ~32 VALU
// ops/tile, hides under MFMA). Kills the standalone cast_x pass (~45us,
// 300MB of HBM traffic).
// 128x128 tile, BK=64, 4 waves (2x2), global_load_lds DMA staging,
// 2-__syncthreads K-step, __launch_bounds__(256,3) (VGPR 64-80, no spill).
// LDS: AFP32 ? 48KB (A-f32 32K + B 16K, 3 blocks/CU) : 32KB (3.2 blocks/CU).
//
// bf16 swizzle (0 conflicts, r4-r15): LDS byte q holds global elem
//   o = q ^ (((q>>7)&7)<<4); read chunk ck[kk] = ((kk*4+g)^(lr&7))<<4.
// fp32-A swizzle (256B rows; bank-audited to the 8-round floor):
//   o = q ^ (((q>>8)&7)<<5) ^ (((q>>11)&1)<<4)   [involution, bits 4-7 only]
//   read: byte = row*256 + kk*128 + g*32, byte ^= ((row&7)<<5)|(((row>>3)&1)<<4)
//   (xor lane-constant: row&7 = lr&7, row bit3 = lr bit3).
// ============================================================================
template <int RELU, int AFP32>
__global__ __launch_bounds__(256, 3) void gemm128h(const void* __restrict__ Araw,
                                                   const u16* __restrict__ Bt,
                                                   const float* __restrict__ bias,
                                                   u16* __restrict__ C,
                                                   int M, int Nc, int K, int NTN) {
  constexpr int ABYTES = AFP32 ? 32768 : 16384;  // A tile bytes (B at +ABYTES)
  __shared__ __align__(16) char smem[AFP32 ? 49152 : 32768];
  const int tid = threadIdx.x;
  const int w = tid >> 6, l = tid & 63;
  const int wm = w >> 1, wn = w & 1;  // 2 x 2 waves
  const int lr = l & 15, g = l >> 4;

  // T1: bijective XCD swizzle (m204)
  const int nwg = gridDim.x;
  const int orig = blockIdx.x;
  const int qq = nwg >> 3, rr = nwg & 7, xcd = orig & 7, idx = orig >> 3;
  const int wgid = (xcd < rr ? xcd * (qq + 1) : rr * (qq + 1) + (xcd - rr) * qq) + idx;
  const int rowBase = (wgid / NTN) * 128;
  const int colBase = (wgid % NTN) * 128;

  const int NT = K >> 6;  // BK = 64

  // A staging pre-swizzle: NA chunks/thread (16B each)
  constexpr int NA = AFP32 ? 8 : 4;
  int sa_row[NA], sa_kel[NA];
#pragma unroll
  for (int p = 0; p < NA; ++p) {
    int q = p * 4096 + w * 1024 + l * 16;
    if (AFP32) {
      int o = q ^ (((q >> 8) & 7) << 5) ^ (((q >> 11) & 1) << 4);
      sa_row[p] = o >> 8;          // row in [0,128)
      sa_kel[p] = (o & 255) >> 2;  // f32 elem in [0,64)
    } else {
      int o = q ^ (((q >> 7) & 7) << 4);
      sa_row[p] = o >> 7;
      sa_kel[p] = (o & 127) >> 1;  // bf16 elem
    }
  }
  // B staging pre-swizzle: 4 chunks/thread
  int sb_row[4], sb_kel[4];
#pragma unroll
  for (int p = 0; p < 4; ++p) {
    int q = p * 4096 + w * 1024 + l * 16;
    int o = q ^ (((q >> 7) & 7) << 4);
    sb_row[p] = o >> 7;
    sb_kel[p] = (o & 127) >> 1;
  }

  f32x4 acc[4][4] = {};

  const int aRowBF = (wm * 64 + lr) * 128;   // bf16-A: byte offset of lane row
  const int aRowF = (wm * 64 + lr) * 256;    // fp32-A
  const int axor = ((lr & 7) << 5) | (((lr >> 3) & 1) << 4);
  const int bRow = (wn * 64 + lr) * 128;
  int ck[2];
  ck[0] = (g ^ (lr & 7)) << 4;        // bf16 kk=0 swizzled 16B chunk
  ck[1] = ((4 + g) ^ (lr & 7)) << 4;  // bf16 kk=1

  for (int t = 0; t < NT; ++t) {
    __syncthreads();  // WAR: all waves done reading previous tile
#pragma unroll
    for (int p = 0; p < NA; ++p) {
      int r = rowBase + sa_row[p];
      if (r >= M) r = M - 1;
      if (AFP32) {
        const float* asrc = (const float*)Araw + (size_t)r * K + t * 64 + sa_kel[p];
        __builtin_amdgcn_global_load_lds(
            (const __attribute__((address_space(1))) void*)asrc,
            (__attribute__((address_space(3))) void*)(smem + p * 4096 + w * 1024), 16, 0, 0);
      } else {
        const u16* asrc = (const u16*)Araw + (size_t)r * K + t * 64 + sa_kel[p];
        __builtin_amdgcn_global_load_lds(
            (const __attribute__((address_space(1))) void*)asrc,
            (__attribute__((address_space(3))) void*)(smem + p * 4096 + w * 1024), 16, 0, 0);
      }
    }
#pragma unroll
    for (int p = 0; p < 4; ++p) {
      int rc = colBase + sb_row[p];
      const u16* bsrc = Bt + (size_t)rc * K + t * 64 + sb_kel[p];
      __builtin_amdgcn_global_load_lds(
          (const __attribute__((address_space(1))) void*)bsrc,
          (__attribute__((address_space(3))) void*)(smem + ABYTES + p * 4096 + w * 1024), 16, 0, 0);
    }
    __syncthreads();  // publish (vmcnt(0) drain hidden by co-resident blocks)

#pragma unroll
    for (int kk = 0; kk < 2; ++kk) {
      bf16x8 af[4], bf[4];
#pragma unroll
      for (int mi = 0; mi < 4; ++mi) {
        if (AFP32) {
          int a0 = (aRowF + mi * 4096 + kk * 128 + g * 32) ^ axor;
          f32x4 lo = *(const f32x4*)(smem + a0);
          f32x4 hi = *(const f32x4*)(smem + (a0 ^ 16));
          union { bf16x8 v; __bf16 e[8]; } cv;
#pragma unroll
          for (int j = 0; j < 4; ++j) {
            cv.e[j] = (__bf16)lo[j];
            cv.e[4 + j] = (__bf16)hi[j];
          }
          af[mi] = cv.v;
        } else {
          af[mi] = *(const bf16x8*)(smem + aRowBF + mi * 2048 + ck[kk]);
        }
      }
#pragma unroll
      for (int ni = 0; ni < 4; ++ni)
        bf[ni] = *(const bf16x8*)(smem + ABYTES + bRow + ni * 2048 + ck[kk]);
      __builtin_amdgcn_s_setprio(1);
#pragma unroll
      for (int mi = 0; mi < 4; ++mi)
#pragma unroll
        for (int ni = 0; ni < 4; ++ni)
          acc[mi][ni] = __builtin_amdgcn_mfma_f32_16x16x32_bf16(af[mi], bf[ni], acc[mi][ni], 0, 0, 0);
      __builtin_amdgcn_s_setprio(0);
    }
  }

  // epilogue: bias + optional relu, bf16 store
  float bv[4];
#pragma unroll
  for (int ni = 0; ni < 4; ++ni) bv[ni] = bias[colBase + wn * 64 + ni * 16 + lr];
#pragma unroll
  for (int mi = 0; mi < 4; ++mi) {
#pragma unroll
    for (int r = 0; r < 4; ++r) {
      int row = rowBase + wm * 64 + mi * 16 + g * 4 + r;
      if (row < M) {
#pragma unroll
        for (int ni = 0; ni < 4; ++ni) {
          float v = acc[mi][ni][r] + bv[ni];
          if (RELU) v = fmaxf(v, 0.f);
          C[(size_t)row * Nc + colBase + wn * 64 + ni * 16 + lr] = f2bf(v);
        }
      }
    }
  }
}

// ---------------- LayerNorm + 4-head proj + sigmoid + exp + seg-sum --------
// z = sigmoid(.) in (0,1) => exp(z) bounded by e: the reference's segmax
// subtraction cancels exactly in e/sum(e), so skip it (verified r14/r15,
// absmax identical 0.001953).
__global__ __launch_bounds__(256) void ln_att_kernel(
    const u16* __restrict__ h2, const float* __restrict__ gam,
    const float* __restrict__ bet, const float* __restrict__ Wa,
    const float* __restrict__ ba, const int* __restrict__ row,
    float* __restrict__ att, float* __restrict__ segsum, int rows) {
  const int w = threadIdx.x >> 6, l = threadIdx.x & 63;
  const int n = blockIdx.x * 4 + w;
  if (n >= rows) return;
  const u16* hp = h2 + (size_t)n * D_IN + l * 8;
  u16x8 hraw = *(const u16x8*)hp;
  float hv[8];
  float s = 0.f, sq = 0.f;
#pragma unroll
  for (int j = 0; j < 8; ++j) {
    hv[j] = bf2f(hraw[j]);
    s += hv[j];
    sq += hv[j] * hv[j];
  }
#pragma unroll
  for (int off = 32; off >= 1; off >>= 1) {
    s += __shfl_xor(s, off);
    sq += __shfl_xor(sq, off);
  }
  const float mean = s * (1.f / 512.f);
  const float var = sq * (1.f / 512.f) - mean * mean;
  const float rstd = rsqrtf(var + 1e-5f);
  float a0 = 0, a1 = 0, a2 = 0, a3 = 0;
#pragma unroll
  for (int j = 0; j < 8; ++j) {
    int d = l * 8 + j;
    float hn = (hv[j] - mean) * rstd * gam[d] + bet[d];
    f32x4 wv = *(const f32x4*)(Wa + (size_t)d * 4);
    a0 += hn * wv[0]; a1 += hn * wv[1]; a2 += hn * wv[2]; a3 += hn * wv[3];
  }
#pragma unroll
  for (int off = 32; off >= 1; off >>= 1) {
    a0 += __shfl_xor(a0, off); a1 += __shfl_xor(a1, off);
    a2 += __shfl_xor(a2, off); a3 += __shfl_xor(a3, off);
  }
  if (l == 0) {
    int rid = row[n];
    float av[4] = {a0, a1, a2, a3};
#pragma unroll
    for (int h = 0; h < 4; ++h) {
      float z = av[h] + ba[h];
      float sg = 1.f / (1.f + expf(-z));
      float e = expf(sg);
      att[(size_t)n * 4 + h] = e;
      atomicAdd(&segsum[(size_t)rid * 4 + h], e);
    }
  }
}

// ---------------- normalize + head-mean ------------------------------------
__global__ void seg_norm(const float* __restrict__ att, const int* __restrict__ row,
                         const float* __restrict__ segsum, float* __restrict__ out) {
  int n = blockIdx.x * 256 + threadIdx.x;
  if (n >= N_ROWS) return;
  int rid = row[n];
  float s = 0.f;
#pragma unroll
  for (int h = 0; h < 4; ++h)
    s += att[(size_t)n * 4 + h] / segsum[(size_t)rid * 4 + h];
  out[n] = 0.25f * s;
}

extern "C" void kernel_launch(void* const* d_in, const int* in_sizes, int n_in,
                              void* d_out, int out_size, void* d_ws, size_t ws_size,
                              hipStream_t stream) {
  const float* x = (const float*)d_in[0];
  const int* row = (const int*)d_in[1];
  const float* alpha = (const float*)d_in[2];
  const float* W1 = (const float*)d_in[3];
  const float* b1 = (const float*)d_in[4];
  const float* W2 = (const float*)d_in[5];
  const float* b2 = (const float*)d_in[6];
  const float* ln_g = (const float*)d_in[7];
  const float* ln_b = (const float*)d_in[8];
  const float* Wa = (const float*)d_in[9];
  const float* ba = (const float*)d_in[10];
  float* out = (float*)d_out;

  char* ws = (char*)d_ws;
  size_t off = 0;
  auto alloc = [&](size_t bytes) {
    void* p = ws + off;
    off += (bytes + 255) & ~(size_t)255;
    return p;
  };
  // fixed buffers (~8 MB)
  u16* W1t = (u16*)alloc((size_t)H_DIM * D_IN * 2);
  u16* W2t = (u16*)alloc((size_t)D_IN * H_DIM * 2);
  float* bias1 = (float*)alloc(H_DIM * 4);
  float* att = (float*)alloc((size_t)N_ROWS * HEADS * 4);
  float* segsum = (float*)alloc(NSEG * HEADS * 4);

  // slab sizing from remaining ws: per-row 5120 B (h1 4KB + h2 1KB)
  const size_t per_row = ((size_t)H_DIM + D_IN) * 2;
  const size_t reserve = (size_t)1 << 20;
  size_t usable = (ws_size > off + reserve) ? (ws_size - off - reserve) : 0;
  long slab_l = (long)(usable / per_row);
  const int maxslab = (N_ROWS + 127) & ~127;  // 100096
  int slab;
  if (slab_l >= maxslab) slab = maxslab;
  else slab = (int)(slab_l & ~127L);          // round DOWN so allocs fit
  if (slab < 128) slab = 128;                 // last-resort minimum

  u16* h1 = (u16*)alloc((size_t)slab * H_DIM * 2);
  u16* h2 = (u16*)alloc((size_t)slab * D_IN * 2);

  init_misc<<<(NSEG * HEADS + 255) / 256, 256, 0, stream>>>(W1, b1, alpha, bias1, segsum);
  transpose_cast<<<dim3(H_DIM / 32, D_IN / 32), dim3(32, 8), 0, stream>>>(W1, W1t, D_IN, H_DIM);
  transpose_cast<<<dim3(D_IN / 32, H_DIM / 32), dim3(32, 8), 0, stream>>>(W2, W2t, H_DIM, D_IN);

  for (int s0 = 0; s0 < N_ROWS; s0 += slab) {
    int rows = N_ROWS - s0 < slab ? N_ROWS - s0 : slab;
    int ntm = (rows + 127) / 128;
    gemm128h<1, 1><<<ntm * (H_DIM / 128), 256, 0, stream>>>(
        (const void*)(x + (size_t)s0 * D_IN), W1t, bias1, h1, rows, H_DIM, D_IN, H_DIM / 128);
    gemm128h<1, 0><<<ntm * (D_IN / 128), 256, 0, stream>>>(
        (const void*)h1, W2t, b2, h2, rows, D_IN, H_DIM, D_IN / 128);
    ln_att_kernel<<<(rows + 3) / 4, 256, 0, stream>>>(
        h2, ln_g, ln_b, Wa, ba, row + s0, att + (size_t)s0 * HEADS, segsum, rows);
  }

  seg_norm<<<(N_ROWS + 255) / 256, 256, 0, stream>>>(att, row, segsum, out);
}

// Round 17
// 688.099 us; speedup vs baseline: 1.0531x; 1.0531x over previous
//
#include <hip/hip_runtime.h>
#include <stdint.h>

#define N_ROWS 100000
#define D_IN 512
#define H_DIM 2048
#define HEADS 4
#define NSEG 10000

typedef unsigned short u16;
typedef __attribute__((ext_vector_type(4))) float f32x4;
typedef __attribute__((ext_vector_type(8))) __bf16 bf16x8;
typedef __attribute__((ext_vector_type(8))) u16 u16x8;
typedef __attribute__((ext_vector_type(4))) u16 u16x4;

__device__ __forceinline__ u16 f2bf(float f) {
  union { float f; uint32_t u; } v; v.f = f;
  uint32_t r = (v.u + 0x7FFF + ((v.u >> 16) & 1)) >> 16;
  return (u16)r;
}
__device__ __forceinline__ float bf2f(u16 u) {
  union { uint32_t u; float f; } v; v.u = ((uint32_t)u) << 16;
  return v.f;
}

// ---------------- init: bias1 = b1 + alpha*W1[512,:], zero segsum ----------
__global__ void init_misc(const float* __restrict__ W1, const float* __restrict__ b1,
                          const float* __restrict__ alpha, float* __restrict__ bias1,
                          float* __restrict__ segsum) {
  int i = blockIdx.x * 256 + threadIdx.x;
  if (i < NSEG * HEADS) segsum[i] = 0.f;
  if (i < H_DIM) bias1[i] = b1[i] + alpha[0] * W1[(size_t)D_IN * H_DIM + i];
}

// ---------------- cast x (fp32) -> xb (bf16) -------------------------------
// Kept as a standalone pass: r16 proved fusing the cast into GEMM1's
// interior (fp32 LDS + cvt at fragment read) costs 133us vs this pass's 45us
// (VALU+2x ds_read in the barrier-to-barrier critical path).
__global__ void cast_x_kernel(const float* __restrict__ x, u16* __restrict__ xb, long n4) {
  long i = (long)blockIdx.x * 256 + threadIdx.x;
  if (i >= n4) return;
  f32x4 v = *(const f32x4*)(x + i * 4);
  u16x4 o;
  o[0] = f2bf(v[0]); o[1] = f2bf(v[1]); o[2] = f2bf(v[2]); o[3] = f2bf(v[3]);
  *(u16x4*)(xb + i * 4) = o;
}

// ---------------- transpose + cast: in[R][C] fp32 -> out[C][R] bf16 --------
__global__ __launch_bounds__(256) void transpose_cast(const float* __restrict__ in,
                                                      u16* __restrict__ outT,
                                                      int R, int Cc) {
  __shared__ float t[32][33];
  const int c0 = blockIdx.x * 32, r0 = blockIdx.y * 32;
  const int tx = threadIdx.x, ty = threadIdx.y;  // 32 x 8
#pragma unroll
  for (int i = 0; i < 4; ++i)
    t[ty + 8 * i][tx] = in[(size_t)(r0 + ty + 8 * i) * Cc + c0 + tx];
  __syncthreads();
#pragma unroll
  for (int i = 0; i < 4; ++i) {
    int oc = ty + 8 * i;
    outT[(size_t)(c0 + oc) * R + r0 + tx] = f2bf(t[tx][oc]);
  }
}

// ============================================================================
// NT GEMM — r11/r15 structure (best known: 690 us total, 285 us/dispatch,
// MfmaUtil 33%, 737 TF/GEMM, 0 bank conflicts, VGPR 64, no spill).
// 128x128 tile, BK=64, 4 waves (2x2), single-buffer LDS 32 KiB,
// global_load_lds DMA staging, 2-__syncthreads K-step, compiler-scheduled
// interior, cross-block overlap from ~4 blocks/CU (m114).
//
// EXHAUSTED LEVERS (r4-r16, do not retry):
//  - gfx950 unified RF: 256 arch-VGPR/SIMD when AGPRs in use. 64 VGPR ->
//    4 waves/SIMD hard cap. (256,5)->48 regs, (512,8)->32 regs => spills,
//    FETCH x17, 2-4x slower (r13/r14).
//  - reg-staged prefetch 1.7x worse than global_load_lds DMA (r12 = m151).
//  - fp32-A staging + cvt in interior: +47% GEMM1 time (r16).
//  - 256^2 deep pipelines: five schedules pinned 27-29% at 2 waves/SIMD;
//    two produced DMA races under graph-replay revalidation (r9).
//  - fused x->h1->h2 MLP: L2-BW-bound at 14% MfmaUtil (r8).
// Swizzle (0 conflicts, r4-r15): LDS byte q holds global elem
// o = q ^ (((q>>7)&7)<<4); read chunks ck[kk] = ((kk*4+g)^(lr&7))<<4.
// ============================================================================
template <int RELU>
__global__ __launch_bounds__(256, 3) void gemm128h(const u16* __restrict__ A,
                                                   const u16* __restrict__ Bt,
                                                   const float* __restrict__ bias,
                                                   u16* __restrict__ C,
                                                   int M, int Nc, int K, int NTN) {
  __shared__ __align__(16) char smem[32768];
  const int tid = threadIdx.x;
  const int w = tid >> 6, l = tid & 63;
  const int wm = w >> 1, wn = w & 1;  // 2 x 2 waves
  const int lr = l & 15, g = l >> 4;

  // T1: bijective XCD swizzle (m204)
  const int nwg = gridDim.x;
  const int orig = blockIdx.x;
  const int qq = nwg >> 3, rr = nwg & 7, xcd = orig & 7, idx = orig >> 3;
  const int wgid = (xcd < rr ? xcd * (qq + 1) : rr * (qq + 1) + (xcd - rr) * qq) + idx;
  const int rowBase = (wgid / NTN) * 128;
  const int colBase = (wgid % NTN) * 128;

  const int NT = K >> 6;  // BK = 64

  // staging source pre-swizzle: 4 chunks/thread per 16 KiB unit.
  int s_row[4], s_kel[4];
#pragma unroll
  for (int p = 0; p < 4; ++p) {
    int q = p * 4096 + w * 1024 + l * 16;
    int o = q ^ (((q >> 7) & 7) << 4);
    s_row[p] = o >> 7;          // row in [0,128)
    s_kel[p] = (o & 127) >> 1;  // k elem in [0,64)
  }

  f32x4 acc[4][4] = {};

  const int aRow = (wm * 64 + lr) * 128;  // byte offset of lane's A row base
  const int bRow = (wn * 64 + lr) * 128;
  int ck[2];
  ck[0] = (g ^ (lr & 7)) << 4;        // kk=0 swizzled 16B chunk
  ck[1] = ((4 + g) ^ (lr & 7)) << 4;  // kk=1 swizzled 16B chunk

  for (int t = 0; t < NT; ++t) {
    __syncthreads();  // WAR: all waves done reading previous tile
#pragma unroll
    for (int p = 0; p < 4; ++p) {
      int r = rowBase + s_row[p];
      if (r >= M) r = M - 1;
      const u16* asrc = A + (size_t)r * K + t * 64 + s_kel[p];
      __builtin_amdgcn_global_load_lds(
          (const __attribute__((address_space(1))) void*)asrc,
          (__attribute__((address_space(3))) void*)(smem + p * 4096 + w * 1024), 16, 0, 0);
    }
#pragma unroll
    for (int p = 0; p < 4; ++p) {
      int rc = colBase + s_row[p];
      const u16* bsrc = Bt + (size_t)rc * K + t * 64 + s_kel[p];
      __builtin_amdgcn_global_load_lds(
          (const __attribute__((address_space(1))) void*)bsrc,
          (__attribute__((address_space(3))) void*)(smem + 16384 + p * 4096 + w * 1024), 16, 0, 0);
    }
    __syncthreads();  // publish (vmcnt(0) drain hidden by co-resident blocks)

#pragma unroll
    for (int kk = 0; kk < 2; ++kk) {
      bf16x8 af[4], bf[4];
#pragma unroll
      for (int mi = 0; mi < 4; ++mi)
        af[mi] = *(const bf16x8*)(smem + aRow + mi * 2048 + ck[kk]);
#pragma unroll
      for (int ni = 0; ni < 4; ++ni)
        bf[ni] = *(const bf16x8*)(smem + 16384 + bRow + ni * 2048 + ck[kk]);
      __builtin_amdgcn_s_setprio(1);
#pragma unroll
      for (int mi = 0; mi < 4; ++mi)
#pragma unroll
        for (int ni = 0; ni < 4; ++ni)
          acc[mi][ni] = __builtin_amdgcn_mfma_f32_16x16x32_bf16(af[mi], bf[ni], acc[mi][ni], 0, 0, 0);
      __builtin_amdgcn_s_setprio(0);
    }
  }

  // epilogue: bias + optional relu, bf16 store
  float bv[4];
#pragma unroll
  for (int ni = 0; ni < 4; ++ni) bv[ni] = bias[colBase + wn * 64 + ni * 16 + lr];
#pragma unroll
  for (int mi = 0; mi < 4; ++mi) {
#pragma unroll
    for (int r = 0; r < 4; ++r) {
      int row = rowBase + wm * 64 + mi * 16 + g * 4 + r;
      if (row < M) {
#pragma unroll
        for (int ni = 0; ni < 4; ++ni) {
          float v = acc[mi][ni][r] + bv[ni];
          if (RELU) v = fmaxf(v, 0.f);
          C[(size_t)row * Nc + colBase + wn * 64 + ni * 16 + lr] = f2bf(v);
        }
      }
    }
  }
}

// ---------------- LayerNorm + 4-head proj + sigmoid + exp + seg-sum --------
// z = sigmoid(.) in (0,1) => exp(z) bounded by e: the reference's segmax
// subtraction cancels exactly in e/sum(e), so skip it (verified r14/r15,
// absmax identical 0.001953).
__global__ __launch_bounds__(256) void ln_att_kernel(
    const u16* __restrict__ h2, const float* __restrict__ gam,
    const float* __restrict__ bet, const float* __restrict__ Wa,
    const float* __restrict__ ba, const int* __restrict__ row,
    float* __restrict__ att, float* __restrict__ segsum, int rows) {
  const int w = threadIdx.x >> 6, l = threadIdx.x & 63;
  const int n = blockIdx.x * 4 + w;
  if (n >= rows) return;
  const u16* hp = h2 + (size_t)n * D_IN + l * 8;
  u16x8 hraw = *(const u16x8*)hp;
  float hv[8];
  float s = 0.f, sq = 0.f;
#pragma unroll
  for (int j = 0; j < 8; ++j) {
    hv[j] = bf2f(hraw[j]);
    s += hv[j];
    sq += hv[j] * hv[j];
  }
#pragma unroll
  for (int off = 32; off >= 1; off >>= 1) {
    s += __shfl_xor(s, off);
    sq += __shfl_xor(sq, off);
  }
  const float mean = s * (1.f / 512.f);
  const float var = sq * (1.f / 512.f) - mean * mean;
  const float rstd = rsqrtf(var + 1e-5f);
  float a0 = 0, a1 = 0, a2 = 0, a3 = 0;
#pragma unroll
  for (int j = 0; j < 8; ++j) {
    int d = l * 8 + j;
    float hn = (hv[j] - mean) * rstd * gam[d] + bet[d];
    f32x4 wv = *(const f32x4*)(Wa + (size_t)d * 4);
    a0 += hn * wv[0]; a1 += hn * wv[1]; a2 += hn * wv[2]; a3 += hn * wv[3];
  }
#pragma unroll
  for (int off = 32; off >= 1; off >>= 1) {
    a0 += __shfl_xor(a0, off); a1 += __shfl_xor(a1, off);
    a2 += __shfl_xor(a2, off); a3 += __shfl_xor(a3, off);
  }
  if (l == 0) {
    int rid = row[n];
    float av[4] = {a0, a1, a2, a3};
#pragma unroll
    for (int h = 0; h < 4; ++h) {
      float z = av[h] + ba[h];
      float sg = 1.f / (1.f + expf(-z));
      float e = expf(sg);
      att[(size_t)n * 4 + h] = e;
      atomicAdd(&segsum[(size_t)rid * 4 + h], e);
    }
  }
}

// ---------------- normalize + head-mean ------------------------------------
__global__ void seg_norm(const float* __restrict__ att, const int* __restrict__ row,
                         const float* __restrict__ segsum, float* __restrict__ out) {
  int n = blockIdx.x * 256 + threadIdx.x;
  if (n >= N_ROWS) return;
  int rid = row[n];
  float s = 0.f;
#pragma unroll
  for (int h = 0; h < 4; ++h)
    s += att[(size_t)n * 4 + h] / segsum[(size_t)rid * 4 + h];
  out[n] = 0.25f * s;
}

extern "C" void kernel_launch(void* const* d_in, const int* in_sizes, int n_in,
                              void* d_out, int out_size, void* d_ws, size_t ws_size,
                              hipStream_t stream) {
  const float* x = (const float*)d_in[0];
  const int* row = (const int*)d_in[1];
  const float* alpha = (const float*)d_in[2];
  const float* W1 = (const float*)d_in[3];
  const float* b1 = (const float*)d_in[4];
  const float* W2 = (const float*)d_in[5];
  const float* b2 = (const float*)d_in[6];
  const float* ln_g = (const float*)d_in[7];
  const float* ln_b = (const float*)d_in[8];
  const float* Wa = (const float*)d_in[9];
  const float* ba = (const float*)d_in[10];
  float* out = (float*)d_out;

  char* ws = (char*)d_ws;
  size_t off = 0;
  auto alloc = [&](size_t bytes) {
    void* p = ws + off;
    off += (bytes + 255) & ~(size_t)255;
    return p;
  };
  // fixed buffers (~8 MB)
  u16* W1t = (u16*)alloc((size_t)H_DIM * D_IN * 2);
  u16* W2t = (u16*)alloc((size_t)D_IN * H_DIM * 2);
  float* bias1 = (float*)alloc(H_DIM * 4);
  float* att = (float*)alloc((size_t)N_ROWS * HEADS * 4);
  float* segsum = (float*)alloc(NSEG * HEADS * 4);

  // slab sizing from remaining ws: per-row 6144 B (xb 1KB + h1 4KB + h2 1KB)
  const size_t per_row = ((size_t)D_IN + H_DIM + D_IN) * 2;
  const size_t reserve = (size_t)1 << 20;
  size_t usable = (ws_size > off + reserve) ? (ws_size - off - reserve) : 0;
  long slab_l = (long)(usable / per_row);
  const int maxslab = (N_ROWS + 127) & ~127;  // 100096
  int slab;
  if (slab_l >= maxslab) slab = maxslab;
  else slab = (int)(slab_l & ~127L);          // round DOWN so allocs fit
  if (slab < 128) slab = 128;                 // last-resort minimum

  u16* xb = (u16*)alloc((size_t)slab * D_IN * 2);
  u16* h1 = (u16*)alloc((size_t)slab * H_DIM * 2);
  u16* h2 = (u16*)alloc((size_t)slab * D_IN * 2);

  init_misc<<<(NSEG * HEADS + 255) / 256, 256, 0, stream>>>(W1, b1, alpha, bias1, segsum);
  transpose_cast<<<dim3(H_DIM / 32, D_IN / 32), dim3(32, 8), 0, stream>>>(W1, W1t, D_IN, H_DIM);
  transpose_cast<<<dim3(D_IN / 32, H_DIM / 32), dim3(32, 8), 0, stream>>>(W2, W2t, H_DIM, D_IN);

  for (int s0 = 0; s0 < N_ROWS; s0 += slab) {
    int rows = N_ROWS - s0 < slab ? N_ROWS - s0 : slab;
    int ntm = (rows + 127) / 128;
    long n4 = (long)rows * D_IN / 4;
    cast_x_kernel<<<(int)((n4 + 255) / 256), 256, 0, stream>>>(x + (size_t)s0 * D_IN, xb, n4);
    gemm128h<1><<<ntm * (H_DIM / 128), 256, 0, stream>>>(
        xb, W1t, bias1, h1, rows, H_DIM, D_IN, H_DIM / 128);
    gemm128h<1><<<ntm * (D_IN / 128), 256, 0, stream>>>(
        h1, W2t, b2, h2, rows, D_IN, H_DIM, D_IN / 128);
    ln_att_kernel<<<(rows + 3) / 4, 256, 0, stream>>>(
        h2, ln_g, ln_b, Wa, ba, row + s0, att + (size_t)s0 * HEADS, segsum, rows);
  }

  seg_norm<<<(N_ROWS + 255) / 256, 256, 0, stream>>>(att, row, segsum, out);
}